// Round 3
// baseline (1912.154 us; speedup 1.0000x reference)
//
#include <hip/hip_runtime.h>
#include <hip/hip_bf16.h>

typedef __hip_bfloat16 bf16_t;

#define NU 100000
#define NI 100000
#define NB_ 5000
#define NC_ 2000
#define NR_ 50000
#define NE 600000
#define NEB 100000
#define NEC 200000
#define NER 400000

__device__ __forceinline__ float b2f(bf16_t x) { return __bfloat162float(x); }
__device__ __forceinline__ float sane(float x) { return isfinite(x) ? x : 0.f; }

// dual-dtype load: external float tensors are either f32 or bf16, decided by flag
__device__ __forceinline__ float ldf(const void* p, size_t i, int f32) {
    return f32 ? ((const float*)p)[i] : __bfloat162float(((const bf16_t*)p)[i]);
}
__device__ __forceinline__ void stf(void* p, size_t i, float v, int f32) {
    if (f32) ((float*)p)[i] = v;
    else     ((bf16_t*)p)[i] = __float2bfloat16(v);
}

// ---- dtype probe: basis_freq[0] == 1.0f exactly. f32 word = 0x3F800000 ----
__global__ void detect_dtype(const unsigned int* w, int* flag) {
    if (threadIdx.x == 0 && blockIdx.x == 0) *flag = (w[0] == 0x3F800000u) ? 1 : 0;
}

// ---- wcomb_r = W_feat_r @ Wr_r (bf16 out, internal) ----
__global__ void combine_w(const void* Wb, const void* Wr0,
                          const void* Wc, const void* Wr1,
                          const void* Wr, const void* Wr2,
                          bf16_t* out, const int* flagp) {
    int f = *flagp;
    const void* A = blockIdx.x == 0 ? Wb : (blockIdx.x == 1 ? Wc : Wr);
    const void* B = blockIdx.x == 0 ? Wr0 : (blockIdx.x == 1 ? Wr1 : Wr2);
    bf16_t* O = out + (size_t)blockIdx.x * 4096;
    for (int idx = threadIdx.x; idx < 4096; idx += blockDim.x) {
        int i = idx >> 6, j = idx & 63;
        float acc = 0.f;
        for (int k = 0; k < 64; ++k)
            acc = fmaf(ldf(A, i * 64 + k, f), ldf(B, k * 64 + j, f), acc);
        O[idx] = __float2bfloat16(acc);
    }
}

// ---- Y[N,64] = X[N,64] @ W[64,64] (X external; W external or internal-bf16) ----
__global__ __launch_bounds__(256) void transform_rows(const void* __restrict__ X,
                                                      const void* __restrict__ W,
                                                      bf16_t* __restrict__ Y, int N,
                                                      const int* flagp, int w_internal) {
    __shared__ float Wl[64 * 64];
    int f = *flagp;
    int wf = w_internal ? 0 : f;
    for (int i = threadIdx.x; i < 4096; i += 256) Wl[i] = ldf(W, i, wf);
    __syncthreads();
    int lane = threadIdx.x & 63;
    int wave = threadIdx.x >> 6;
    int r = blockIdx.x * 4 + wave;
    if (r >= N) return;
    float rv = ldf(X, (size_t)r * 64 + lane, f);
    float acc = 0.f;
#pragma unroll
    for (int k = 0; k < 64; ++k) {
        float xk = __shfl(rv, k, 64);
        acc = fmaf(xk, Wl[k * 64 + lane], acc);
    }
    Y[(size_t)r * 64 + lane] = __float2bfloat16(acc);
}

__global__ __launch_bounds__(256) void count_edges(const int* __restrict__ dst,
                                                   float* __restrict__ cnt, int n) {
    int t = blockIdx.x * blockDim.x + threadIdx.x;
    if (t < n) atomicAdd(cnt + dst[t], 1.0f);
}

// ---- edge pass 1: exp(logit) + segment sums ----
__global__ __launch_bounds__(256) void edge_logits(
    const bf16_t* __restrict__ uh, const bf16_t* __restrict__ ih,
    const void* __restrict__ u_pos_k, const void* __restrict__ i_pos_k,
    const void* __restrict__ basis_freq, const void* __restrict__ phase,
    const void* __restrict__ e_time,
    const int* __restrict__ e_iid, const int* __restrict__ e_uid,
    const int* __restrict__ pos_u, const int* __restrict__ pos_i,
    float* __restrict__ p_lu, float* __restrict__ p_sh, float* __restrict__ p_li,
    float* __restrict__ sum_lu, float* __restrict__ sum_su,
    float* __restrict__ sum_li, float* __restrict__ sum_si,
    const int* flagp) {
    int f = *flagp;
    int lane = threadIdx.x & 63;
    int e = (blockIdx.x * blockDim.x + threadIdx.x) >> 6;
    if (e >= NE) return;
    int iid = e_iid[e], uid = e_uid[e], pu = pos_u[e], pi = pos_i[e];
    float t = ldf(e_time, e, f);
    float te = cosf(fmaf(t, ldf(basis_freq, lane, f), ldf(phase, lane, f)));
    float hi = b2f(ih[(size_t)iid * 64 + lane]);
    float hu = b2f(uh[(size_t)uid * 64 + lane]);
    float upk = ldf(u_pos_k, pu * 64 + lane, f);
    float ipk = ldf(i_pos_k, pi * 64 + lane, f);
    float d_lu = (hi + upk + te) * hu;
    float d_sh = hi * hu;
    float d_li = (hu + ipk + te) * hi;
#pragma unroll
    for (int off = 32; off; off >>= 1) {
        d_lu += __shfl_xor(d_lu, off, 64);
        d_sh += __shfl_xor(d_sh, off, 64);
        d_li += __shfl_xor(d_li, off, 64);
    }
    if (lane == 0) {
        float p1 = expf(fminf(d_lu * 0.125f, 50.f));
        float p2 = expf(fminf(d_sh * 0.125f, 50.f));
        float p3 = expf(fminf(d_li * 0.125f, 50.f));
        p_lu[e] = p1; p_sh[e] = p2; p_li[e] = p3;
        atomicAdd(sum_lu + uid, p1);
        atomicAdd(sum_su + uid, p2);
        atomicAdd(sum_li + iid, p3);
        atomicAdd(sum_si + iid, p2);
    }
}

// ---- edge pass 2a: user-side scatter for uid in [lo,hi) ----
__global__ __launch_bounds__(256) void edge_accum_user(
    const bf16_t* __restrict__ uh, const bf16_t* __restrict__ ih,
    const void* __restrict__ u_pos,
    const int* __restrict__ e_iid, const int* __restrict__ e_uid,
    const int* __restrict__ pos_u,
    const float* __restrict__ p_lu, const float* __restrict__ p_sh,
    const float* __restrict__ sum_lu, const float* __restrict__ sum_su,
    float* __restrict__ acc, int lo, int hi, const int* flagp) {
    int lane = threadIdx.x & 63;
    int e = (blockIdx.x * blockDim.x + threadIdx.x) >> 6;
    if (e >= NE) return;
    int uid = e_uid[e];
    if (uid < lo || uid >= hi) return;
    int f = *flagp;
    int iid = e_iid[e], pu = pos_u[e];
    float hi_v = b2f(ih[(size_t)iid * 64 + lane]);
    float a_long  = p_lu[e] / (sum_lu[uid] + 1e-9f);
    float a_short = p_sh[e] / (sum_su[uid] + 1e-9f);
    float up = ldf(u_pos, pu * 64 + lane, f);
    size_t rb = (size_t)(uid - lo) * 128;
    atomicAdd(acc + rb + lane,      a_long * (hi_v + up));
    atomicAdd(acc + rb + 64 + lane, a_short * hi_v);
}

// ---- edge pass 2b: item-side scatter for iid in [lo,hi) ----
__global__ __launch_bounds__(256) void edge_accum_item(
    const bf16_t* __restrict__ uh, const bf16_t* __restrict__ ih,
    const void* __restrict__ i_pos,
    const int* __restrict__ e_iid, const int* __restrict__ e_uid,
    const int* __restrict__ pos_i,
    const float* __restrict__ p_li, const float* __restrict__ p_sh,
    const float* __restrict__ sum_li, const float* __restrict__ sum_si,
    float* __restrict__ acc, int lo, int hi, const int* flagp) {
    int lane = threadIdx.x & 63;
    int e = (blockIdx.x * blockDim.x + threadIdx.x) >> 6;
    if (e >= NE) return;
    int iid = e_iid[e];
    if (iid < lo || iid >= hi) return;
    int f = *flagp;
    int uid = e_uid[e], pi = pos_i[e];
    float hu = b2f(uh[(size_t)uid * 64 + lane]);
    float b_long  = p_li[e] / (sum_li[iid] + 1e-9f);
    float b_short = p_sh[e] / (sum_si[iid] + 1e-9f);
    float ip = ldf(i_pos, pi * 64 + lane, f);
    size_t rb = (size_t)(iid - lo) * 128;
    atomicAdd(acc + rb + lane,      b_long * (hu + ip));
    atomicAdd(acc + rb + 64 + lane, b_short * hu);
}

// ---- relation scatter for dst in [lo,hi): rel[dst-lo] += fW[src]/cnt[dst] ----
__global__ __launch_bounds__(256) void rel_scatter(const bf16_t* __restrict__ fW,
                                                   const int* __restrict__ src,
                                                   const int* __restrict__ dst,
                                                   const float* __restrict__ cnt,
                                                   float* __restrict__ rel, int n,
                                                   int lo, int hi) {
    int lane = threadIdx.x & 63;
    int e = (blockIdx.x * blockDim.x + threadIdx.x) >> 6;
    if (e >= n) return;
    int dI = dst[e];
    if (dI < lo || dI >= hi) return;
    int sI = src[e];
    float inv = 1.0f / fmaxf(cnt[dI], 1.0f);
    atomicAdd(rel + (size_t)(dI - lo) * 64 + lane, b2f(fW[(size_t)sI * 64 + lane]) * inv);
}

// ---- user epilogue for rows [lo,hi): out = elu(acc @ Wg_u + user_h) ----
__global__ __launch_bounds__(256) void user_out_kernel(const float* __restrict__ acc,
                                                       const void* __restrict__ Wg_u,
                                                       const void* __restrict__ user_h,
                                                       void* __restrict__ out,
                                                       const int* flagp, int lo, int hi) {
    __shared__ float Wl[128 * 64];
    int f = *flagp;
    for (int i = threadIdx.x; i < 128 * 64; i += 256) Wl[i] = ldf(Wg_u, i, f);
    __syncthreads();
    int lane = threadIdx.x & 63;
    int wave = threadIdx.x >> 6;
    int r = lo + blockIdx.x * 4 + wave;
    if (r >= hi) return;
    size_t rb = (size_t)(r - lo) * 128;
    float a0 = acc[rb + lane];
    float a1 = acc[rb + 64 + lane];
    float s = ldf(user_h, (size_t)r * 64 + lane, f);
#pragma unroll
    for (int k = 0; k < 64; ++k) {
        s = fmaf(__shfl(a0, k, 64), Wl[k * 64 + lane], s);
        s = fmaf(__shfl(a1, k, 64), Wl[(64 + k) * 64 + lane], s);
    }
    float v = s > 0.f ? s : expm1f(s);
    stf(out, (size_t)r * 64 + lane, sane(v), f);
}

// ---- item epilogue for rows [lo,hi): out = elu(acc @ Wg_i + rel + item_h) ----
__global__ __launch_bounds__(256) void item_out_kernel(const float* __restrict__ acc,
                                                       const float* __restrict__ rel,
                                                       const void* __restrict__ Wg_i,
                                                       const void* __restrict__ item_h,
                                                       void* __restrict__ out,
                                                       const int* flagp, int lo, int hi) {
    __shared__ float Wl[128 * 64];
    int f = *flagp;
    for (int i = threadIdx.x; i < 128 * 64; i += 256) Wl[i] = ldf(Wg_i, i, f);
    __syncthreads();
    int lane = threadIdx.x & 63;
    int wave = threadIdx.x >> 6;
    int r = lo + blockIdx.x * 4 + wave;
    if (r >= hi) return;
    size_t rb = (size_t)(r - lo) * 128;
    float a0 = acc[rb + lane];
    float a1 = acc[rb + 64 + lane];
    float s = ldf(item_h, (size_t)r * 64 + lane, f) + rel[(size_t)(r - lo) * 64 + lane];
#pragma unroll
    for (int k = 0; k < 64; ++k) {
        s = fmaf(__shfl(a0, k, 64), Wl[k * 64 + lane], s);
        s = fmaf(__shfl(a1, k, 64), Wl[(64 + k) * 64 + lane], s);
    }
    float v = s > 0.f ? s : expm1f(s);
    stf(out, (size_t)(NU + r) * 64 + lane, sane(v), f);
}

extern "C" void kernel_launch(void* const* d_in, const int* in_sizes, int n_in,
                              void* d_out, int out_size, void* d_ws, size_t ws_size,
                              hipStream_t stream) {
    const void* user_h     = d_in[0];
    const void* item_h     = d_in[1];
    const void* brand_feat = d_in[2];
    const void* cat_feat   = d_in[3];
    const void* rel_feat   = d_in[4];
    const void* Wu   = d_in[5];
    const void* Wi   = d_in[6];
    const void* Wb   = d_in[7];
    const void* Wc   = d_in[8];
    const void* Wr   = d_in[9];
    const void* Wg_u = d_in[10];
    const void* Wg_i = d_in[11];
    const void* u_pos   = d_in[12];
    const void* u_pos_k = d_in[13];
    const void* i_pos   = d_in[14];
    const void* i_pos_k = d_in[15];
    const void* basis_freq = d_in[16];
    const void* phase      = d_in[17];
    const void* Wr0 = d_in[18];
    const void* Wr1 = d_in[19];
    const void* Wr2 = d_in[20];
    const void* e_time = d_in[21];
    const int* e_iid  = (const int*)d_in[22];
    const int* e_uid  = (const int*)d_in[23];
    const int* pos_u  = (const int*)d_in[24];
    const int* pos_i  = (const int*)d_in[25];
    const int* eb_src = (const int*)d_in[26];
    const int* eb_dst = (const int*)d_in[27];
    const int* ec_src = (const int*)d_in[28];
    const int* ec_dst = (const int*)d_in[29];
    const int* er_src = (const int*)d_in[30];
    const int* er_dst = (const int*)d_in[31];

    // ---- fixed workspace layout ----
    char* base = (char*)d_ws;
    size_t off = 0;
    auto alloc = [&](size_t bytes) { size_t p = off; off = (off + bytes + 511) & ~(size_t)511; return p; };
    size_t o_flag  = alloc(512);
    size_t o_uh    = alloc((size_t)NU * 64 * 2);
    size_t o_ih    = alloc((size_t)NI * 64 * 2);
    size_t o_pbuf  = alloc((size_t)3 * NE * 4);
    size_t o_fW    = alloc((size_t)(NB_ + NC_ + NR_) * 64 * 2);
    size_t o_wcomb = alloc((size_t)3 * 4096 * 2);
    size_t o_cnt   = alloc((size_t)3 * NI * 4);
    size_t o_sums  = alloc((size_t)(2 * NU + 2 * NI) * 4);
    size_t fixed_end = off;

    int*    flagp = (int*)(base + o_flag);
    bf16_t* uh    = (bf16_t*)(base + o_uh);
    bf16_t* ih    = (bf16_t*)(base + o_ih);
    float*  pbuf  = (float*)(base + o_pbuf);
    bf16_t* fW    = (bf16_t*)(base + o_fW);
    bf16_t* fWb   = fW;
    bf16_t* fWc   = fW + (size_t)NB_ * 64;
    bf16_t* fWr   = fW + (size_t)(NB_ + NC_) * 64;
    bf16_t* wcomb = (bf16_t*)(base + o_wcomb);
    float*  cnt   = (float*)(base + o_cnt);
    float*  sums  = (float*)(base + o_sums);
    float* sum_lu = sums;
    float* sum_su = sums + NU;
    float* sum_li = sums + 2 * (size_t)NU;
    float* sum_si = sums + 2 * (size_t)NU + NI;
    float* p_lu = pbuf;
    float* p_sh = pbuf + NE;
    float* p_li = pbuf + 2 * (size_t)NE;

    // ---- chunked accumulator region (adaptive to ws_size; host-side, constant) ----
    size_t avail = (ws_size > fixed_end + 65536) ? (ws_size - fixed_end - 65536) : (size_t)1;
    size_t userBytes = (size_t)NU * 128 * 4;                 // 51.2 MB
    size_t itemBytes = (size_t)NI * 192 * 4;                 // 76.8 MB (acc + rel)
    int KU = (int)((userBytes + avail - 1) / avail); if (KU < 1) KU = 1; if (KU > 64) KU = 64;
    int KI = (int)((itemBytes + avail - 1) / avail); if (KI < 1) KI = 1; if (KI > 64) KI = 64;
    int CU = (NU + KU - 1) / KU;
    int CI = (NI + KI - 1) / KI;
    float* acc = (float*)(base + fixed_end);
    float* relc = acc + (size_t)CI * 128;

    // zero cnt + sums (contiguous)
    hipMemsetAsync(base + o_cnt, 0, fixed_end - o_cnt, stream);

    detect_dtype<<<1, 64, 0, stream>>>((const unsigned int*)basis_freq, flagp);

    combine_w<<<3, 256, 0, stream>>>(Wb, Wr0, Wc, Wr1, Wr, Wr2, wcomb, flagp);
    transform_rows<<<NU / 4, 256, 0, stream>>>(user_h, Wu, uh, NU, flagp, 0);
    transform_rows<<<NI / 4, 256, 0, stream>>>(item_h, Wi, ih, NI, flagp, 0);
    transform_rows<<<(NB_ + 3) / 4, 256, 0, stream>>>(brand_feat, wcomb, fWb, NB_, flagp, 1);
    transform_rows<<<(NC_ + 3) / 4, 256, 0, stream>>>(cat_feat, wcomb + 4096, fWc, NC_, flagp, 1);
    transform_rows<<<(NR_ + 3) / 4, 256, 0, stream>>>(rel_feat, wcomb + 8192, fWr, NR_, flagp, 1);

    count_edges<<<(NEB + 255) / 256, 256, 0, stream>>>(eb_dst, cnt, NEB);
    count_edges<<<(NEC + 255) / 256, 256, 0, stream>>>(ec_dst, cnt + NI, NEC);
    count_edges<<<(NER + 255) / 256, 256, 0, stream>>>(er_dst, cnt + 2 * NI, NER);

    edge_logits<<<NE / 4, 256, 0, stream>>>(uh, ih, u_pos_k, i_pos_k, basis_freq, phase,
                                            e_time, e_iid, e_uid, pos_u, pos_i,
                                            p_lu, p_sh, p_li,
                                            sum_lu, sum_su, sum_li, sum_si, flagp);

    // ---- user phase (chunked) ----
    for (int c = 0; c < KU; ++c) {
        int lo = c * CU, hi = lo + CU > NU ? NU : lo + CU;
        hipMemsetAsync(acc, 0, (size_t)CU * 128 * 4, stream);
        edge_accum_user<<<NE / 4, 256, 0, stream>>>(uh, ih, u_pos, e_iid, e_uid, pos_u,
                                                    p_lu, p_sh, sum_lu, sum_su,
                                                    acc, lo, hi, flagp);
        user_out_kernel<<<(CU + 3) / 4, 256, 0, stream>>>(acc, Wg_u, user_h, d_out,
                                                          flagp, lo, hi);
    }

    // ---- item phase (chunked) ----
    for (int c = 0; c < KI; ++c) {
        int lo = c * CI, hi = lo + CI > NI ? NI : lo + CI;
        hipMemsetAsync(acc, 0, (size_t)CI * 192 * 4, stream);
        edge_accum_item<<<NE / 4, 256, 0, stream>>>(uh, ih, i_pos, e_iid, e_uid, pos_i,
                                                    p_li, p_sh, sum_li, sum_si,
                                                    acc, lo, hi, flagp);
        rel_scatter<<<(NEB + 3) / 4, 256, 0, stream>>>(fWb, eb_src, eb_dst, cnt, relc, NEB, lo, hi);
        rel_scatter<<<(NEC + 3) / 4, 256, 0, stream>>>(fWc, ec_src, ec_dst, cnt + NI, relc, NEC, lo, hi);
        rel_scatter<<<(NER + 3) / 4, 256, 0, stream>>>(fWr, er_src, er_dst, cnt + 2 * NI, relc, NER, lo, hi);
        item_out_kernel<<<(CI + 3) / 4, 256, 0, stream>>>(acc, relc, Wg_i, item_h, d_out,
                                                          flagp, lo, hi);
    }
}